// Round 6
// baseline (155.761 us; speedup 1.0000x reference)
//
#include <hip/hip_runtime.h>
#include <math.h>

#define BN 8192
#define CN 1000
#define DN 128
#define INVT (1.0f/0.3f)
#define EXP2C 4.80898346962988f   // (1/0.3) * log2(e)

typedef __bf16 bf16x8 __attribute__((ext_vector_type(8)));
typedef float  f32x4  __attribute__((ext_vector_type(4)));

// ws layout in floats
#define F_FEATN  0          // 8192*128
#define F_MEANSN 1048576    // 1000*128
#define F_XX     1176576    // 8192
#define F_YY     1184768    // 1000
#define F_DIAG   1185768    // 8192
#define F_FEATB  1193960    // 8192*128 bf16
#define F_MEANSB 1718248    // 1024*128 bf16 (raw, zero-padded)
#define F_CEROW  1783784    // 8192
#define F_MROW   1791976    // 8192
#define F_POSR   1800168    // 8192
#define F_PM     1808360    // 2*8192 CE partial max
#define F_PL     1824744    // 2*8192 CE partial sum
#define F_BOT    1841128    // 8192  -- zeroed region start
#define F_CNT    1849320    // 1000 ints
#define F_CSUM   1850320    // 1000*128 (zeroed)

// mega-kernel block ranges (no LDS, no barriers — waves independent)
#define NB_NSD  128   // 512 waves: 32 rows x 512-col half each
#define NB_SCL  272   // 1088 waves: 64 rows x <=8 triangular j-tiles
#define NB_CSUM 256

// -------- feat: L2-normalize + bf16 copy + diag + label histogram --------
__global__ void norm_feat(const float* __restrict__ src, float* __restrict__ dst,
                          float* __restrict__ sq, __bf16* __restrict__ dstb,
                          float* __restrict__ diag, const int* __restrict__ labels,
                          int* __restrict__ counts) {
    int row = blockIdx.x * 4 + (threadIdx.x >> 6);
    int lane = threadIdx.x & 63;
    float f0 = src[row * DN + lane];
    float f1 = src[row * DN + 64 + lane];
    float ss = f0 * f0 + f1 * f1;
    #pragma unroll
    for (int o = 32; o > 0; o >>= 1) ss += __shfl_xor(ss, o);
    float inv = 1.0f / fmaxf(sqrtf(ss), 1e-12f);
    float n0 = f0 * inv, n1 = f1 * inv;
    dst[row * DN + lane] = n0;
    dst[row * DN + 64 + lane] = n1;
    __bf16 b0 = (__bf16)n0, b1 = (__bf16)n1;
    dstb[row * DN + lane] = b0;
    dstb[row * DN + 64 + lane] = b1;
    float fb0 = (float)b0, fb1 = (float)b1;
    float sb = fb0 * fb0 + fb1 * fb1;
    #pragma unroll
    for (int o = 32; o > 0; o >>= 1) sb += __shfl_xor(sb, o);
    if (lane == 0) {
        diag[row] = sb;
        sq[row] = ss * inv * inv;
        atomicAdd(&counts[labels[row]], 1);
    }
}

// -------- means: normalize (fp32) + yy + raw-bf16 copy padded to 1024 rows --------
__global__ void norm_means(const float* __restrict__ src, float* __restrict__ dst,
                           float* __restrict__ sq, __bf16* __restrict__ dstb) {
    int row = blockIdx.x * 4 + (threadIdx.x >> 6);   // 0..1023
    int lane = threadIdx.x & 63;
    float f0 = (row < CN) ? src[row * DN + lane] : 0.f;
    float f1 = (row < CN) ? src[row * DN + 64 + lane] : 0.f;
    dstb[row * DN + lane] = (__bf16)f0;
    dstb[row * DN + 64 + lane] = (__bf16)f1;
    if (row >= CN) return;
    float ss = f0 * f0 + f1 * f1;
    #pragma unroll
    for (int o = 32; o > 0; o >>= 1) ss += __shfl_xor(ss, o);
    float inv = 1.0f / fmaxf(sqrtf(ss), 1e-12f);
    dst[row * DN + lane] = f0 * inv;
    dst[row * DN + 64 + lane] = f1 * inv;
    if (lane == 0) sq[row] = ss;
}

// load 4 B-fragments (one k-chunk of a 64-col tile) straight from global/L2
__device__ __forceinline__ void loadB4(bf16x8* b, const uint4* __restrict__ src,
                                       int j0, int kk, int l15, int q) {
    #pragma unroll
    for (int jj = 0; jj < 4; jj++)
        b[jj] = *(const bf16x8*)&src[(size_t)(j0 + jj * 16 + l15) * 16 + kk * 4 + q];
}

// -------- mega kernel (LDS-free): [0,128) nsd | [128,400) scl-tri | [400,656) csum --------
__global__ __launch_bounds__(256, 2) void mega_kernel(
        const __bf16* __restrict__ featb, const __bf16* __restrict__ meansb,
        const float* __restrict__ featn, const int* __restrict__ labels,
        const float* __restrict__ xx, const float* __restrict__ yy,
        float* __restrict__ out, float* __restrict__ pm, float* __restrict__ pl,
        float* __restrict__ bottom, float* __restrict__ csum) {
    int bx = blockIdx.x;
    int tid = threadIdx.x;
    int lane = tid & 63, w = tid >> 6;
    int q = lane >> 4, l15 = lane & 15;

    if (bx < NB_NSD) {
        // ---- NSD: wave = 32 rows x 512 cols, full local online-softmax ----
        int wid = bx * 4 + w;             // 0..511
        int ib = wid >> 1, h = wid & 1;
        int i0 = ib * 32;
        const uint4* fv = (const uint4*)featb;
        const uint4* mv = (const uint4*)meansb;
        bf16x8 af[2][4];
        #pragma unroll
        for (int ii = 0; ii < 2; ii++)
            #pragma unroll
            for (int kk = 0; kk < 4; kk++)
                af[ii][kk] = *(const bf16x8*)&fv[(size_t)(i0 + ii * 16 + l15) * 16 + kk * 4 + q];
        float mrow[2][4], srow[2][4], xa[2][4];
        int la[2][4];
        #pragma unroll
        for (int ii = 0; ii < 2; ii++) {
            int rbase = i0 + ii * 16 + q * 4;
            int4 lv = ((const int4*)labels)[rbase >> 2];
            float4 xv = ((const float4*)xx)[rbase >> 2];
            la[ii][0] = lv.x; la[ii][1] = lv.y; la[ii][2] = lv.z; la[ii][3] = lv.w;
            xa[ii][0] = xv.x; xa[ii][1] = xv.y; xa[ii][2] = xv.z; xa[ii][3] = xv.w;
            #pragma unroll
            for (int r4 = 0; r4 < 4; r4++) { mrow[ii][r4] = -INFINITY; srow[ii][r4] = 0.f; }
        }
        for (int jt = 0; jt < 8; jt++) {
            int j0 = h * 512 + jt * 64;
            f32x4 acc[2][4];
            #pragma unroll
            for (int ii = 0; ii < 2; ii++)
                #pragma unroll
                for (int jj = 0; jj < 4; jj++) acc[ii][jj] = (f32x4){0.f, 0.f, 0.f, 0.f};
            bf16x8 b[2][4];
            loadB4(b[0], mv, j0, 0, l15, q);
            #pragma unroll
            for (int kk = 0; kk < 4; kk++) {
                if (kk < 3) loadB4(b[(kk + 1) & 1], mv, j0, kk + 1, l15, q);
                #pragma unroll
                for (int ii = 0; ii < 2; ii++)
                    #pragma unroll
                    for (int jj = 0; jj < 4; jj++)
                        acc[ii][jj] = __builtin_amdgcn_mfma_f32_16x16x32_bf16(
                            af[ii][kk], b[kk & 1][jj], acc[ii][jj], 0, 0, 0);
            }
            int jgl[4]; float yv[4];
            #pragma unroll
            for (int jj = 0; jj < 4; jj++) {
                jgl[jj] = j0 + jj * 16 + l15;
                yv[jj] = (jgl[jj] < CN) ? yy[jgl[jj]] : 0.f;
            }
            #pragma unroll
            for (int ii = 0; ii < 2; ii++)
                #pragma unroll
                for (int r4 = 0; r4 < 4; r4++) {
                    int ig = i0 + ii * 16 + q * 4 + r4;
                    float tm = -INFINITY, vv[4];
                    #pragma unroll
                    for (int jj = 0; jj < 4; jj++) {
                        float v = -0.5f * (xa[ii][r4] - 2.f * acc[ii][jj][r4] + yv[jj]);
                        bool ok = (jgl[jj] < CN);
                        if (ok) out[(size_t)ig * CN + jgl[jj]] = v;
                        float l = (jgl[jj] == la[ii][r4]) ? 1.5f * v : v;
                        vv[jj] = ok ? l : -INFINITY;
                        tm = fmaxf(tm, vv[jj]);
                    }
                    float ts = 0.f;
                    #pragma unroll
                    for (int jj = 0; jj < 4; jj++) ts += __expf(vv[jj] - tm);
                    float M = fmaxf(mrow[ii][r4], tm);
                    srow[ii][r4] = srow[ii][r4] * __expf(mrow[ii][r4] - M) + ts * __expf(tm - M);
                    mrow[ii][r4] = M;
                }
        }
        #pragma unroll
        for (int ii = 0; ii < 2; ii++)
            #pragma unroll
            for (int r4 = 0; r4 < 4; r4++) {
                float m = mrow[ii][r4], s = srow[ii][r4];
                #pragma unroll
                for (int o = 8; o > 0; o >>= 1) {
                    float mo = __shfl_xor(m, o), so = __shfl_xor(s, o);
                    float M = fmaxf(m, mo);
                    s = s * __expf(m - M) + so * __expf(mo - M);
                    m = M;
                }
                if (l15 == 0) {
                    int ig = i0 + ii * 16 + q * 4 + r4;
                    pm[h * BN + ig] = m;
                    pl[h * BN + ig] = s;
                }
            }

    } else if (bx < NB_NSD + NB_SCL) {
        // ---- SCL: wave = 64 i-rows x chunk of <=8 j-tiles (64-col), J >= I ----
        int cid = (bx - NB_NSD) * 4 + w;       // 0..1087
        int g = 0, cap;
        while (cid >= (cap = 8 * (16 - g))) { cid -= cap; ++g; }
        int per = 16 - g;
        int io = 0;
        while (cid >= per) { cid -= per; ++io; }
        int I = 8 * g + io;
        int J0 = I + 8 * cid;
        int jend = min(J0 + 8, 128);
        int i0 = I * 64;
        const uint4* fv = (const uint4*)featb;

        bf16x8 af[4][4];
        #pragma unroll
        for (int ii = 0; ii < 4; ii++)
            #pragma unroll
            for (int kk = 0; kk < 4; kk++)
                af[ii][kk] = *(const bf16x8*)&fv[(size_t)(i0 + ii * 16 + l15) * 16 + kk * 4 + q];
        float bs[4][4] = {};

        for (int J = J0; J < jend; J++) {
            int j0 = J * 64;
            f32x4 acc[4][4];
            #pragma unroll
            for (int ii = 0; ii < 4; ii++)
                #pragma unroll
                for (int jj = 0; jj < 4; jj++) acc[ii][jj] = (f32x4){0.f, 0.f, 0.f, 0.f};
            bf16x8 b[2][4];
            loadB4(b[0], fv, j0, 0, l15, q);
            #pragma unroll
            for (int kk = 0; kk < 4; kk++) {
                if (kk < 3) loadB4(b[(kk + 1) & 1], fv, j0, kk + 1, l15, q);
                #pragma unroll
                for (int ii = 0; ii < 4; ii++)
                    #pragma unroll
                    for (int jj = 0; jj < 4; jj++)
                        acc[ii][jj] = __builtin_amdgcn_mfma_f32_16x16x32_bf16(
                            af[ii][kk], b[kk & 1][jj], acc[ii][jj], 0, 0, 0);
            }
            float cp[4] = {0.f, 0.f, 0.f, 0.f};
            #pragma unroll
            for (int ii = 0; ii < 4; ii++)
                #pragma unroll
                for (int jj = 0; jj < 4; jj++)
                    #pragma unroll
                    for (int r4 = 0; r4 < 4; r4++) {
                        float e = exp2f(acc[ii][jj][r4] * EXP2C);
                        bs[ii][r4] += e;
                        cp[jj] += e;
                    }
            if (J != I) {      // mirror: column sums -> bottom[j] (skip diagonal tile)
                #pragma unroll
                for (int jj = 0; jj < 4; jj++) {
                    float c = cp[jj];
                    c += __shfl_xor(c, 16);
                    c += __shfl_xor(c, 32);
                    if (lane < 16)
                        atomicAdd(&bottom[j0 + jj * 16 + l15], c);
                }
            }
        }
        #pragma unroll
        for (int ii = 0; ii < 4; ii++)
            #pragma unroll
            for (int r4 = 0; r4 < 4; r4++) {
                float bsum = bs[ii][r4];
                #pragma unroll
                for (int o = 8; o > 0; o >>= 1) bsum += __shfl_xor(bsum, o);
                if (l15 == 0) atomicAdd(&bottom[i0 + ii * 16 + q * 4 + r4], bsum);
            }

    } else {
        // ---- csum: class-sum vectors via atomics ----
        int b2 = bx - NB_NSD - NB_SCL;
        for (int idx = b2 * 256 + tid; idx < BN * DN; idx += NB_CSUM * 256) {
            int row = idx >> 7, d = idx & 127;
            atomicAdd(&csum[labels[row] * DN + d], featn[idx]);
        }
    }
}

// -------- fused: margin + pos dots + CE final (2 partials + out-gather) --------
__global__ void cemp_kernel(const float* __restrict__ featn, const float* __restrict__ meansn,
        const float* __restrict__ csum, const int* __restrict__ labels,
        const float* __restrict__ pm, const float* __restrict__ pl,
        const float* __restrict__ out, float* __restrict__ m_row,
        float* __restrict__ pos_row, float* __restrict__ ce_row) {
    int row = blockIdx.x * 4 + (threadIdx.x >> 6);
    int lane = threadIdx.x & 63;
    int lab = labels[row];
    float f0 = featn[row * DN + lane],  f1 = featn[row * DN + 64 + lane];
    float m0 = meansn[lab * DN + lane], m1 = meansn[lab * DN + 64 + lane];
    float c0 = csum[lab * DN + lane],   c1 = csum[lab * DN + 64 + lane];
    float d0 = f0 - m0, d1 = f1 - m1;
    float ss = d0 * d0 + d1 * d1;
    float pp = f0 * c0 + f1 * c1;
    #pragma unroll
    for (int o = 32; o > 0; o >>= 1) {
        ss += __shfl_xor(ss, o);
        pp += __shfl_xor(pp, o);
    }
    if (lane == 0) {
        m_row[row] = ss;
        pos_row[row] = pp;
        float ma = pm[row], mb = pm[BN + row];
        float M = fmaxf(ma, mb);
        float S = pl[row] * __expf(ma - M) + pl[BN + row] * __expf(mb - M);
        ce_row[row] = (M + logf(S)) - 1.5f * out[(size_t)row * CN + lab];
    }
}

__global__ void final_kernel(const float* __restrict__ bottom, const float* __restrict__ pos_row,
        const int* __restrict__ labels, const int* __restrict__ counts,
        const float* __restrict__ ce_row, const float* __restrict__ m_row,
        const float* __restrict__ diag, const float* __restrict__ xx,
        float* __restrict__ loss_out) {
    int tid = threadIdx.x;
    float sp = 0.f, nv = 0.f, ce = 0.f, mg = 0.f;
    for (int i = tid; i < BN; i += 256) {
        ce += ce_row[i];
        mg += m_row[i];
        float bot = bottom[i] - __expf(diag[i] * INVT);   // exclude j==i (bf16 diag)
        float pv = (pos_row[i] - xx[i]) * INVT;           // exclude j==i (fp32), apply 1/T
        int c = counts[labels[i]] - 1;
        if (c > 0) {
            sp += pv / (float)c - logf(bot);
            nv += 1.f;
        }
    }
    #pragma unroll
    for (int o = 32; o > 0; o >>= 1) {
        sp += __shfl_xor(sp, o);
        nv += __shfl_xor(nv, o);
        ce += __shfl_xor(ce, o);
        mg += __shfl_xor(mg, o);
    }
    __shared__ float r1[4], r2[4], r3[4], r4[4];
    int w = tid >> 6, lane = tid & 63;
    if (lane == 0) { r1[w] = sp; r2[w] = nv; r3[w] = ce; r4[w] = mg; }
    __syncthreads();
    if (tid == 0) {
        float SP = r1[0] + r1[1] + r1[2] + r1[3];
        float NV = r2[0] + r2[1] + r2[2] + r2[3];
        float CE = r3[0] + r3[1] + r3[2] + r3[3];
        float MG = r4[0] + r4[1] + r4[2] + r4[3];
        float scl = -SP / fmaxf(NV, 1.f);
        loss_out[0] = 0.9f * (CE / (float)BN) + 0.1f * scl + 0.5f * (MG / (2.f * (float)BN));
    }
}

extern "C" void kernel_launch(void* const* d_in, const int* in_sizes, int n_in,
                              void* d_out, int out_size, void* d_ws, size_t ws_size,
                              hipStream_t stream) {
    const float* feat   = (const float*)d_in[0];
    const int*   labels = (const int*)d_in[1];
    const float* means  = (const float*)d_in[2];
    float* out = (float*)d_out;
    float* ws  = (float*)d_ws;

    float*  featn  = ws + F_FEATN;
    float*  meansn = ws + F_MEANSN;
    float*  xx     = ws + F_XX;
    float*  yy     = ws + F_YY;
    float*  diag   = ws + F_DIAG;
    __bf16* featb  = (__bf16*)(ws + F_FEATB);
    __bf16* meansb = (__bf16*)(ws + F_MEANSB);
    float*  ce_row = ws + F_CEROW;
    float*  m_row  = ws + F_MROW;
    float*  posr   = ws + F_POSR;
    float*  pm     = ws + F_PM;
    float*  pl     = ws + F_PL;
    float*  bottom = ws + F_BOT;
    int*    counts = (int*)(ws + F_CNT);
    float*  csum   = ws + F_CSUM;

    // zero bottom + counts + csum (contiguous)
    hipMemsetAsync(ws + F_BOT, 0, (size_t)(8192 + 1000 + 128000) * sizeof(float), stream);

    norm_feat<<<2048, 256, 0, stream>>>(feat, featn, xx, featb, diag, labels, counts);
    norm_means<<<256, 256, 0, stream>>>(means, meansn, yy, meansb);
    mega_kernel<<<NB_NSD + NB_SCL + NB_CSUM, 256, 0, stream>>>(
        featb, meansb, featn, labels, xx, yy, out, pm, pl, bottom, csum);
    cemp_kernel<<<2048, 256, 0, stream>>>(featn, meansn, csum, labels, pm, pl, out,
                                          m_row, posr, ce_row);
    final_kernel<<<1, 256, 0, stream>>>(bottom, posr, labels, counts, ce_row, m_row,
                                        diag, xx, out + (size_t)BN * CN);
}